// Round 1
// baseline (146.625 us; speedup 1.0000x reference)
//
#include <hip/hip_runtime.h>

#define NCAM 5
#define NC 15
#define FH 128
#define FW 240
#define CUBE 64
#define NVOX (CUBE*CUBE*CUBE)
#define THREADS 256
#define BLOCKS_PER_B (NVOX/THREADS)   // 1024

__global__ __launch_bounds__(THREADS) void proj_kernel(
    const float* __restrict__ fm,        // [NCAM][B][NC][FH][FW]
    const float* __restrict__ gc,        // [B][7]
    const float* __restrict__ space_center,  // [3]
    const float* __restrict__ space_size,    // [3]
    const float* __restrict__ sub_size,      // [3]
    const float* __restrict__ centers,   // [B][NCAM][2]
    const float* __restrict__ trans,     // [B][NCAM][2][3]
    const float* __restrict__ cam_R,     // [B][NCAM][3][3]
    const float* __restrict__ cam_T,     // [B][NCAM][3]
    const float* __restrict__ cam_f,     // [B][NCAM][2]
    const float* __restrict__ cam_c,     // [B][NCAM][2]
    float* __restrict__ out, int B)
{
    const int b = blockIdx.x / BLOCKS_PER_B;            // scalar (blockIdx-derived)
    const int n = (blockIdx.x % BLOCKS_PER_B) * THREADS + threadIdx.x;

    // ---- per-b scalar setup (replicates reference arithmetic exactly) ----
    float ctlf[3], fnf[3], sc[3], ssz[3];
    int   ctl[3], st[3], en[3];
    #pragma unroll
    for (int d = 0; d < 3; ++d) {
        ssz[d] = space_size[d];
        sc[d]  = space_center[d];
        float sub = sub_size[d];
        int fn = (int)(ssz[d] / sub * (CUBE - 1.0f)) + 1;   // trunc like .astype(int32)
        fnf[d] = (float)fn;
        float scale = (fnf[d] - 1.0f) / ssz[d];
        float bias  = -sub / 2.0f / ssz[d] * (fnf[d] - 1.0f)
                      - scale * (sc[d] - ssz[d] / 2.0f);
        int c_tl = (int)rintf(gc[b*7 + d] * scale + bias);  // jnp.round = half-to-even
        ctl[d]  = c_tl;
        ctlf[d] = (float)c_tl;
        int mask = 0;
        if (d < 2) {
            mask = (int)((1.0f - gc[b*7 + 5 + d]) / 2.0f * (CUBE - 1.0f));
            if (mask < 0) mask = 0;
        }
        st[d] = max(c_tl + mask, 0);
        int e = min(c_tl + CUBE - mask, fn);
        en[d] = max(e, st[d] + 1);
    }

    // ---- offset output (3 threads per b) ----
    if (n < 3) {
        int d = n;
        float off = ctlf[d] / (fnf[d] - 1.0f) * ssz[d]
                    - ssz[d] / 2.0f + sub_size[d] / 2.0f;
        out[(size_t)B * NC * NVOX + b*3 + d] = off;
    }

    const int vi = n >> 12, vj = (n >> 6) & 63, vk = n & 63;
    const int fx = ctl[0] + vi, fy = ctl[1] + vj, fz = ctl[2] + vk;
    const bool valid = (fx >= st[0]) & (fx < en[0])
                     & (fy >= st[1]) & (fy < en[1])
                     & (fz >= st[2]) & (fz < en[2])
                     & (gc[b*7 + 3] >= 0.0f);

    float acc[NC];
    #pragma unroll
    for (int c = 0; c < NC; ++c) acc[c] = 0.0f;

    if (valid) {
        const float wxw = sc[0] - ssz[0]*0.5f + (float)fx / (fnf[0]-1.0f) * ssz[0];
        const float wyw = sc[1] - ssz[1]*0.5f + (float)fy / (fnf[1]-1.0f) * ssz[1];
        const float wzw = sc[2] - ssz[2]*0.5f + (float)fz / (fnf[2]-1.0f) * ssz[2];

        for (int cam = 0; cam < NCAM; ++cam) {
            const int bk = b*NCAM + cam;
            const float* R = cam_R + bk*9;
            const float* T = cam_T + bk*3;
            float r0 = wxw - T[0], r1 = wyw - T[1], r2 = wzw - T[2];
            float X0 = R[0]*r0 + R[1]*r1 + R[2]*r2;
            float X1 = R[3]*r0 + R[4]*r1 + R[5]*r2;
            float X2 = R[6]*r0 + R[7]*r1 + R[8]*r2;
            float px = cam_f[bk*2+0]*X0/X2 + cam_c[bk*2+0];
            float py = cam_f[bk*2+1]*X1/X2 + cam_c[bk*2+1];
            float maxwh = fmaxf(centers[bk*2+0]*2.0f, centers[bk*2+1]*2.0f);
            px = fminf(fmaxf(px, -1.0f), maxwh);
            py = fminf(fmaxf(py, -1.0f), maxwh);
            const float* tr = trans + bk*6;
            float tx = (tr[0]*px + tr[1]*py + tr[2]) * 0.25f;  // HM_W/IMG_W
            float ty = (tr[3]*px + tr[4]*py + tr[5]) * 0.25f;  // HM_H/IMG_H
            float gx = fminf(fmaxf(tx/239.0f*2.0f - 1.0f, -1.1f), 1.1f);
            float gy = fminf(fmaxf(ty/127.0f*2.0f - 1.0f, -1.1f), 1.1f);

            float ixf = (gx + 1.0f)*(FW*0.5f) - 0.5f;
            float iyf = (gy + 1.0f)*(FH*0.5f) - 0.5f;
            float x0f = floorf(ixf), y0f = floorf(iyf);
            float wx1 = ixf - x0f,  wy1 = iyf - y0f;
            float wx0 = 1.0f - wx1, wy0 = 1.0f - wy1;
            int x0 = (int)x0f, y0 = (int)y0f;
            int x1 = x0 + 1,   y1 = y0 + 1;
            bool vx0 = (x0 >= 0) & (x0 <= FW-1);
            bool vx1 = (x1 >= 0) & (x1 <= FW-1);
            bool vy0 = (y0 >= 0) & (y0 <= FH-1);
            bool vy1 = (y1 >= 0) & (y1 <= FH-1);
            float w00 = wx0*wy0*(float)(vx0 & vy0);
            float w10 = wx1*wy0*(float)(vx1 & vy0);
            float w01 = wx0*wy1*(float)(vx0 & vy1);
            float w11 = wx1*wy1*(float)(vx1 & vy1);
            int xc0 = min(max(x0,0),FW-1), xc1 = min(max(x1,0),FW-1);
            int yc0 = min(max(y0,0),FH-1), yc1 = min(max(y1,0),FH-1);
            int o00 = yc0*FW + xc0, o10 = yc0*FW + xc1;
            int o01 = yc1*FW + xc0, o11 = yc1*FW + xc1;
            const float* base = fm + ((size_t)(cam*B + b)) * NC * FH * FW;
            #pragma unroll
            for (int c = 0; c < NC; ++c) {
                const float* p = base + c*(FH*FW);
                acc[c] += w00*p[o00] + w10*p[o10] + w01*p[o01] + w11*p[o11];
            }
        }
    }

    const float invd = (float)(5.0 + 1e-6);   // n_cam + 1e-6
    #pragma unroll
    for (int c = 0; c < NC; ++c) {
        float v = acc[c] / invd;
        v = fminf(fmaxf(v, 0.0f), 1.0f);
        out[((size_t)(b*NC + c)) * NVOX + n] = v;
    }
}

extern "C" void kernel_launch(void* const* d_in, const int* in_sizes, int n_in,
                              void* d_out, int out_size, void* d_ws, size_t ws_size,
                              hipStream_t stream) {
    const float* fm        = (const float*)d_in[0];
    const float* gc        = (const float*)d_in[1];
    const float* space_c   = (const float*)d_in[2];
    const float* space_s   = (const float*)d_in[3];
    const float* sub_s     = (const float*)d_in[4];
    // d_in[5] = sub_cube_size (64), fixed at compile time
    const float* centers   = (const float*)d_in[6];
    const float* trans     = (const float*)d_in[7];
    const float* cam_R     = (const float*)d_in[8];
    const float* cam_T     = (const float*)d_in[9];
    const float* cam_f     = (const float*)d_in[10];
    const float* cam_c     = (const float*)d_in[11];
    float* out = (float*)d_out;
    const int B = in_sizes[1] / 7;

    dim3 grid(B * BLOCKS_PER_B), block(THREADS);
    hipLaunchKernelGGL(proj_kernel, grid, block, 0, stream,
                       fm, gc, space_c, space_s, sub_s,
                       centers, trans, cam_R, cam_T, cam_f, cam_c, out, B);
}

// Round 2
// 68.827 us; speedup vs baseline: 2.1303x; 2.1303x over previous
//
#include <hip/hip_runtime.h>

#define NCAM 5
#define NC 15
#define NCP 16              // padded channels (one 64B cache line per pixel)
#define FH 128
#define FW 240
#define HW (FH*FW)
#define CUBE 64
#define NVOX (CUBE*CUBE*CUBE)
#define THREADS 256
#define BLOCKS_PER_B (NVOX/THREADS)   // 1024

// ---- pre-pass: [cam][b][c][h][w] -> [cam][b][h][w][16] (channel-last, padded)
__global__ __launch_bounds__(THREADS) void transpose_fm(
    const float* __restrict__ fm, float* __restrict__ fmT)
{
    const int p  = blockIdx.x * THREADS + threadIdx.x;  // pixel in (cam,b)
    const int cb = blockIdx.y;                          // cam*B + b
    const float* src = fm + (size_t)cb * NC * HW + p;
    float v[NCP];
    #pragma unroll
    for (int c = 0; c < NC; ++c) v[c] = src[(size_t)c * HW];
    v[15] = 0.0f;
    float* dst = fmT + ((size_t)cb * HW + p) * NCP;
    #pragma unroll
    for (int q = 0; q < 4; ++q)
        *(float4*)(dst + 4*q) = make_float4(v[4*q], v[4*q+1], v[4*q+2], v[4*q+3]);
}

// ---- main kernel: one thread per (b, voxel), channel-last gathers
__global__ __launch_bounds__(THREADS) void proj_main(
    const float* __restrict__ fmT,       // [NCAM][B][HW][16]
    const float* __restrict__ gc,        // [B][7]
    const float* __restrict__ space_center,
    const float* __restrict__ space_size,
    const float* __restrict__ sub_size,
    const float* __restrict__ centers,
    const float* __restrict__ trans,
    const float* __restrict__ cam_R,
    const float* __restrict__ cam_T,
    const float* __restrict__ cam_f,
    const float* __restrict__ cam_c,
    float* __restrict__ out, int B)
{
    const int b = blockIdx.x / BLOCKS_PER_B;
    const int n = (blockIdx.x % BLOCKS_PER_B) * THREADS + threadIdx.x;

    float ctlf[3], fnf[3], sc[3], ssz[3];
    int   ctl[3], st[3], en[3];
    #pragma unroll
    for (int d = 0; d < 3; ++d) {
        ssz[d] = space_size[d];
        sc[d]  = space_center[d];
        float sub = sub_size[d];
        int fn = (int)(ssz[d] / sub * (CUBE - 1.0f)) + 1;
        fnf[d] = (float)fn;
        float scale = (fnf[d] - 1.0f) / ssz[d];
        float bias  = -sub / 2.0f / ssz[d] * (fnf[d] - 1.0f)
                      - scale * (sc[d] - ssz[d] / 2.0f);
        int c_tl = (int)rintf(gc[b*7 + d] * scale + bias);
        ctl[d]  = c_tl;
        ctlf[d] = (float)c_tl;
        int mask = 0;
        if (d < 2) {
            mask = (int)((1.0f - gc[b*7 + 5 + d]) / 2.0f * (CUBE - 1.0f));
            if (mask < 0) mask = 0;
        }
        st[d] = max(c_tl + mask, 0);
        int e = min(c_tl + CUBE - mask, fn);
        en[d] = max(e, st[d] + 1);
    }

    if (n < 3) {
        int d = n;
        float off = ctlf[d] / (fnf[d] - 1.0f) * ssz[d]
                    - ssz[d] / 2.0f + sub_size[d] / 2.0f;
        out[(size_t)B * NC * NVOX + b*3 + d] = off;
    }

    const int vi = n >> 12, vj = (n >> 6) & 63, vk = n & 63;
    const int fx = ctl[0] + vi, fy = ctl[1] + vj, fz = ctl[2] + vk;
    const bool valid = (fx >= st[0]) & (fx < en[0])
                     & (fy >= st[1]) & (fy < en[1])
                     & (fz >= st[2]) & (fz < en[2])
                     & (gc[b*7 + 3] >= 0.0f);

    float acc[NCP];
    #pragma unroll
    for (int c = 0; c < NCP; ++c) acc[c] = 0.0f;

    if (valid) {
        const float wxw = sc[0] - ssz[0]*0.5f + (float)fx / (fnf[0]-1.0f) * ssz[0];
        const float wyw = sc[1] - ssz[1]*0.5f + (float)fy / (fnf[1]-1.0f) * ssz[1];
        const float wzw = sc[2] - ssz[2]*0.5f + (float)fz / (fnf[2]-1.0f) * ssz[2];

        for (int cam = 0; cam < NCAM; ++cam) {
            const int bk = b*NCAM + cam;
            const float* R = cam_R + bk*9;
            const float* T = cam_T + bk*3;
            float r0 = wxw - T[0], r1 = wyw - T[1], r2 = wzw - T[2];
            float X0 = R[0]*r0 + R[1]*r1 + R[2]*r2;
            float X1 = R[3]*r0 + R[4]*r1 + R[5]*r2;
            float X2 = R[6]*r0 + R[7]*r1 + R[8]*r2;
            float px = cam_f[bk*2+0]*X0/X2 + cam_c[bk*2+0];
            float py = cam_f[bk*2+1]*X1/X2 + cam_c[bk*2+1];
            float maxwh = fmaxf(centers[bk*2+0]*2.0f, centers[bk*2+1]*2.0f);
            px = fminf(fmaxf(px, -1.0f), maxwh);
            py = fminf(fmaxf(py, -1.0f), maxwh);
            const float* tr = trans + bk*6;
            float tx = (tr[0]*px + tr[1]*py + tr[2]) * 0.25f;   // HM_W/IMG_W
            float ty = (tr[3]*px + tr[4]*py + tr[5]) * 0.25f;   // HM_H/IMG_H
            float gx = fminf(fmaxf(tx/239.0f*2.0f - 1.0f, -1.1f), 1.1f);
            float gy = fminf(fmaxf(ty/127.0f*2.0f - 1.0f, -1.1f), 1.1f);

            float ixf = (gx + 1.0f)*(FW*0.5f) - 0.5f;
            float iyf = (gy + 1.0f)*(FH*0.5f) - 0.5f;
            float x0f = floorf(ixf), y0f = floorf(iyf);
            float wx1 = ixf - x0f,  wy1 = iyf - y0f;
            float wx0 = 1.0f - wx1, wy0 = 1.0f - wy1;
            int x0 = (int)x0f, y0 = (int)y0f;
            int x1 = x0 + 1,   y1 = y0 + 1;
            bool vx0 = (x0 >= 0) & (x0 <= FW-1);
            bool vx1 = (x1 >= 0) & (x1 <= FW-1);
            bool vy0 = (y0 >= 0) & (y0 <= FH-1);
            bool vy1 = (y1 >= 0) & (y1 <= FH-1);
            float w00 = wx0*wy0*(float)(vx0 & vy0);
            float w10 = wx1*wy0*(float)(vx1 & vy0);
            float w01 = wx0*wy1*(float)(vx0 & vy1);
            float w11 = wx1*wy1*(float)(vx1 & vy1);
            int xc0 = min(max(x0,0),FW-1), xc1 = min(max(x1,0),FW-1);
            int yc0 = min(max(y0,0),FH-1), yc1 = min(max(y1,0),FH-1);
            int o00 = yc0*FW + xc0, o10 = yc0*FW + xc1;
            int o01 = yc1*FW + xc0, o11 = yc1*FW + xc1;

            const float* base = fmT + ((size_t)(cam*B + b)) * HW * NCP;

            #define DO_TAP(Wt, Ot)                                            \
            {                                                                 \
                const float* tp = base + (size_t)(Ot) * NCP;                  \
                _Pragma("unroll")                                             \
                for (int q = 0; q < 4; ++q) {                                 \
                    float4 v = *(const float4*)(tp + 4*q);                    \
                    acc[4*q+0] = fmaf((Wt), v.x, acc[4*q+0]);                 \
                    acc[4*q+1] = fmaf((Wt), v.y, acc[4*q+1]);                 \
                    acc[4*q+2] = fmaf((Wt), v.z, acc[4*q+2]);                 \
                    acc[4*q+3] = fmaf((Wt), v.w, acc[4*q+3]);                 \
                }                                                             \
            }
            DO_TAP(w00, o00)
            DO_TAP(w10, o10)
            DO_TAP(w01, o01)
            DO_TAP(w11, o11)
            #undef DO_TAP
        }
    }

    const float invd = (float)(5.0 + 1e-6);
    #pragma unroll
    for (int c = 0; c < NC; ++c) {
        float v = acc[c] / invd;
        v = fminf(fmaxf(v, 0.0f), 1.0f);
        out[((size_t)(b*NC + c)) * NVOX + n] = v;
    }
}

// ---- fallback (round-1 kernel) if ws is too small for staging ----
__global__ __launch_bounds__(THREADS) void proj_fallback(
    const float* __restrict__ fm,
    const float* __restrict__ gc,
    const float* __restrict__ space_center,
    const float* __restrict__ space_size,
    const float* __restrict__ sub_size,
    const float* __restrict__ centers,
    const float* __restrict__ trans,
    const float* __restrict__ cam_R,
    const float* __restrict__ cam_T,
    const float* __restrict__ cam_f,
    const float* __restrict__ cam_c,
    float* __restrict__ out, int B)
{
    const int b = blockIdx.x / BLOCKS_PER_B;
    const int n = (blockIdx.x % BLOCKS_PER_B) * THREADS + threadIdx.x;

    float ctlf[3], fnf[3], sc[3], ssz[3];
    int   ctl[3], st[3], en[3];
    #pragma unroll
    for (int d = 0; d < 3; ++d) {
        ssz[d] = space_size[d];
        sc[d]  = space_center[d];
        float sub = sub_size[d];
        int fn = (int)(ssz[d] / sub * (CUBE - 1.0f)) + 1;
        fnf[d] = (float)fn;
        float scale = (fnf[d] - 1.0f) / ssz[d];
        float bias  = -sub / 2.0f / ssz[d] * (fnf[d] - 1.0f)
                      - scale * (sc[d] - ssz[d] / 2.0f);
        int c_tl = (int)rintf(gc[b*7 + d] * scale + bias);
        ctl[d]  = c_tl;
        ctlf[d] = (float)c_tl;
        int mask = 0;
        if (d < 2) {
            mask = (int)((1.0f - gc[b*7 + 5 + d]) / 2.0f * (CUBE - 1.0f));
            if (mask < 0) mask = 0;
        }
        st[d] = max(c_tl + mask, 0);
        int e = min(c_tl + CUBE - mask, fn);
        en[d] = max(e, st[d] + 1);
    }
    if (n < 3) {
        int d = n;
        float off = ctlf[d] / (fnf[d] - 1.0f) * ssz[d]
                    - ssz[d] / 2.0f + sub_size[d] / 2.0f;
        out[(size_t)B * NC * NVOX + b*3 + d] = off;
    }
    const int vi = n >> 12, vj = (n >> 6) & 63, vk = n & 63;
    const int fx = ctl[0] + vi, fy = ctl[1] + vj, fz = ctl[2] + vk;
    const bool valid = (fx >= st[0]) & (fx < en[0])
                     & (fy >= st[1]) & (fy < en[1])
                     & (fz >= st[2]) & (fz < en[2])
                     & (gc[b*7 + 3] >= 0.0f);
    float acc[NC];
    #pragma unroll
    for (int c = 0; c < NC; ++c) acc[c] = 0.0f;
    if (valid) {
        const float wxw = sc[0] - ssz[0]*0.5f + (float)fx / (fnf[0]-1.0f) * ssz[0];
        const float wyw = sc[1] - ssz[1]*0.5f + (float)fy / (fnf[1]-1.0f) * ssz[1];
        const float wzw = sc[2] - ssz[2]*0.5f + (float)fz / (fnf[2]-1.0f) * ssz[2];
        for (int cam = 0; cam < NCAM; ++cam) {
            const int bk = b*NCAM + cam;
            const float* R = cam_R + bk*9;
            const float* T = cam_T + bk*3;
            float r0 = wxw - T[0], r1 = wyw - T[1], r2 = wzw - T[2];
            float X0 = R[0]*r0 + R[1]*r1 + R[2]*r2;
            float X1 = R[3]*r0 + R[4]*r1 + R[5]*r2;
            float X2 = R[6]*r0 + R[7]*r1 + R[8]*r2;
            float px = cam_f[bk*2+0]*X0/X2 + cam_c[bk*2+0];
            float py = cam_f[bk*2+1]*X1/X2 + cam_c[bk*2+1];
            float maxwh = fmaxf(centers[bk*2+0]*2.0f, centers[bk*2+1]*2.0f);
            px = fminf(fmaxf(px, -1.0f), maxwh);
            py = fminf(fmaxf(py, -1.0f), maxwh);
            const float* tr = trans + bk*6;
            float tx = (tr[0]*px + tr[1]*py + tr[2]) * 0.25f;
            float ty = (tr[3]*px + tr[4]*py + tr[5]) * 0.25f;
            float gx = fminf(fmaxf(tx/239.0f*2.0f - 1.0f, -1.1f), 1.1f);
            float gy = fminf(fmaxf(ty/127.0f*2.0f - 1.0f, -1.1f), 1.1f);
            float ixf = (gx + 1.0f)*(FW*0.5f) - 0.5f;
            float iyf = (gy + 1.0f)*(FH*0.5f) - 0.5f;
            float x0f = floorf(ixf), y0f = floorf(iyf);
            float wx1 = ixf - x0f,  wy1 = iyf - y0f;
            float wx0 = 1.0f - wx1, wy0 = 1.0f - wy1;
            int x0 = (int)x0f, y0 = (int)y0f;
            int x1 = x0 + 1,   y1 = y0 + 1;
            bool vx0 = (x0 >= 0) & (x0 <= FW-1);
            bool vx1 = (x1 >= 0) & (x1 <= FW-1);
            bool vy0 = (y0 >= 0) & (y0 <= FH-1);
            bool vy1 = (y1 >= 0) & (y1 <= FH-1);
            float w00 = wx0*wy0*(float)(vx0 & vy0);
            float w10 = wx1*wy0*(float)(vx1 & vy0);
            float w01 = wx0*wy1*(float)(vx0 & vy1);
            float w11 = wx1*wy1*(float)(vx1 & vy1);
            int xc0 = min(max(x0,0),FW-1), xc1 = min(max(x1,0),FW-1);
            int yc0 = min(max(y0,0),FH-1), yc1 = min(max(y1,0),FH-1);
            int o00 = yc0*FW + xc0, o10 = yc0*FW + xc1;
            int o01 = yc1*FW + xc0, o11 = yc1*FW + xc1;
            const float* base = fm + ((size_t)(cam*B + b)) * NC * HW;
            #pragma unroll
            for (int c = 0; c < NC; ++c) {
                const float* p = base + c*HW;
                acc[c] += w00*p[o00] + w10*p[o10] + w01*p[o01] + w11*p[o11];
            }
        }
    }
    const float invd = (float)(5.0 + 1e-6);
    #pragma unroll
    for (int c = 0; c < NC; ++c) {
        float v = acc[c] / invd;
        v = fminf(fmaxf(v, 0.0f), 1.0f);
        out[((size_t)(b*NC + c)) * NVOX + n] = v;
    }
}

extern "C" void kernel_launch(void* const* d_in, const int* in_sizes, int n_in,
                              void* d_out, int out_size, void* d_ws, size_t ws_size,
                              hipStream_t stream) {
    const float* fm        = (const float*)d_in[0];
    const float* gc        = (const float*)d_in[1];
    const float* space_c   = (const float*)d_in[2];
    const float* space_s   = (const float*)d_in[3];
    const float* sub_s     = (const float*)d_in[4];
    const float* centers   = (const float*)d_in[6];
    const float* trans     = (const float*)d_in[7];
    const float* cam_R     = (const float*)d_in[8];
    const float* cam_T     = (const float*)d_in[9];
    const float* cam_f     = (const float*)d_in[10];
    const float* cam_c     = (const float*)d_in[11];
    float* out = (float*)d_out;
    const int B = in_sizes[1] / 7;

    const size_t need = (size_t)NCAM * B * HW * NCP * sizeof(float);
    if (ws_size >= need) {
        float* fmT = (float*)d_ws;
        dim3 tg(HW / THREADS, NCAM * B);
        hipLaunchKernelGGL(transpose_fm, tg, dim3(THREADS), 0, stream, fm, fmT);
        dim3 grid(B * BLOCKS_PER_B), block(THREADS);
        hipLaunchKernelGGL(proj_main, grid, block, 0, stream,
                           fmT, gc, space_c, space_s, sub_s,
                           centers, trans, cam_R, cam_T, cam_f, cam_c, out, B);
    } else {
        dim3 grid(B * BLOCKS_PER_B), block(THREADS);
        hipLaunchKernelGGL(proj_fallback, grid, block, 0, stream,
                           fm, gc, space_c, space_s, sub_s,
                           centers, trans, cam_R, cam_T, cam_f, cam_c, out, B);
    }
}

// Round 3
// 54.909 us; speedup vs baseline: 2.6703x; 1.2535x over previous
//
#include <hip/hip_runtime.h>
#include <hip/hip_fp16.h>

#define NCAM 5
#define NC 15
#define NCP 16              // padded channels; fp16 -> 32 B per pixel
#define FH 128
#define FW 240
#define HW (FH*FW)
#define CUBE 64
#define NVOX (CUBE*CUBE*CUBE)
#define THREADS 256
#define BLOCKS_PER_B (NVOX/THREADS)   // 1024

// ---- pre-pass: [cam][b][c][h][w] f32 -> [cam][b][h][w][16] f16 (channel-last)
__global__ __launch_bounds__(THREADS) void transpose_fm(
    const float* __restrict__ fm, __half* __restrict__ fmH)
{
    const int p  = blockIdx.x * THREADS + threadIdx.x;  // pixel in (cam,b)
    const int cb = blockIdx.y;                          // cam*B + b
    const float* src = fm + (size_t)cb * NC * HW + p;
    __half v[NCP];
    #pragma unroll
    for (int c = 0; c < NC; ++c) v[c] = __float2half(src[(size_t)c * HW]);
    v[15] = __float2half(0.0f);
    uint4* dst = (uint4*)(fmH + ((size_t)cb * HW + p) * NCP);
    dst[0] = *(const uint4*)(v);
    dst[1] = *(const uint4*)(v + 8);
}

// ---- main kernel: one thread per (b, voxel), fp16 channel-last gathers
__global__ __launch_bounds__(THREADS) void proj_main(
    const __half* __restrict__ fmH,      // [NCAM][B][HW][16] f16
    const float* __restrict__ gc,        // [B][7]
    const float* __restrict__ space_center,
    const float* __restrict__ space_size,
    const float* __restrict__ sub_size,
    const float* __restrict__ centers,
    const float* __restrict__ trans,
    const float* __restrict__ cam_R,
    const float* __restrict__ cam_T,
    const float* __restrict__ cam_f,
    const float* __restrict__ cam_c,
    float* __restrict__ out, int B)
{
    const int b = blockIdx.x / BLOCKS_PER_B;
    const int n = (blockIdx.x % BLOCKS_PER_B) * THREADS + threadIdx.x;

    float ctlf[3], fnf[3], sc[3], ssz[3];
    int   ctl[3], st[3], en[3];
    #pragma unroll
    for (int d = 0; d < 3; ++d) {
        ssz[d] = space_size[d];
        sc[d]  = space_center[d];
        float sub = sub_size[d];
        int fn = (int)(ssz[d] / sub * (CUBE - 1.0f)) + 1;
        fnf[d] = (float)fn;
        float scale = (fnf[d] - 1.0f) / ssz[d];
        float bias  = -sub / 2.0f / ssz[d] * (fnf[d] - 1.0f)
                      - scale * (sc[d] - ssz[d] / 2.0f);
        int c_tl = (int)rintf(gc[b*7 + d] * scale + bias);
        ctl[d]  = c_tl;
        ctlf[d] = (float)c_tl;
        int mask = 0;
        if (d < 2) {
            mask = (int)((1.0f - gc[b*7 + 5 + d]) / 2.0f * (CUBE - 1.0f));
            if (mask < 0) mask = 0;
        }
        st[d] = max(c_tl + mask, 0);
        int e = min(c_tl + CUBE - mask, fn);
        en[d] = max(e, st[d] + 1);
    }

    if (n < 3) {
        int d = n;
        float off = ctlf[d] / (fnf[d] - 1.0f) * ssz[d]
                    - ssz[d] / 2.0f + sub_size[d] / 2.0f;
        out[(size_t)B * NC * NVOX + b*3 + d] = off;
    }

    const int vi = n >> 12, vj = (n >> 6) & 63, vk = n & 63;
    const int fx = ctl[0] + vi, fy = ctl[1] + vj, fz = ctl[2] + vk;
    const bool valid = (fx >= st[0]) & (fx < en[0])
                     & (fy >= st[1]) & (fy < en[1])
                     & (fz >= st[2]) & (fz < en[2])
                     & (gc[b*7 + 3] >= 0.0f);

    float acc[NCP];
    #pragma unroll
    for (int c = 0; c < NCP; ++c) acc[c] = 0.0f;

    if (valid) {
        const float wxw = sc[0] - ssz[0]*0.5f + (float)fx / (fnf[0]-1.0f) * ssz[0];
        const float wyw = sc[1] - ssz[1]*0.5f + (float)fy / (fnf[1]-1.0f) * ssz[1];
        const float wzw = sc[2] - ssz[2]*0.5f + (float)fz / (fnf[2]-1.0f) * ssz[2];

        for (int cam = 0; cam < NCAM; ++cam) {
            const int bk = b*NCAM + cam;
            const float* R = cam_R + bk*9;
            const float* T = cam_T + bk*3;
            float r0 = wxw - T[0], r1 = wyw - T[1], r2 = wzw - T[2];
            float X0 = R[0]*r0 + R[1]*r1 + R[2]*r2;
            float X1 = R[3]*r0 + R[4]*r1 + R[5]*r2;
            float X2 = R[6]*r0 + R[7]*r1 + R[8]*r2;
            float px = cam_f[bk*2+0]*X0/X2 + cam_c[bk*2+0];
            float py = cam_f[bk*2+1]*X1/X2 + cam_c[bk*2+1];
            float maxwh = fmaxf(centers[bk*2+0]*2.0f, centers[bk*2+1]*2.0f);
            px = fminf(fmaxf(px, -1.0f), maxwh);
            py = fminf(fmaxf(py, -1.0f), maxwh);
            const float* tr = trans + bk*6;
            float tx = (tr[0]*px + tr[1]*py + tr[2]) * 0.25f;   // HM_W/IMG_W
            float ty = (tr[3]*px + tr[4]*py + tr[5]) * 0.25f;   // HM_H/IMG_H
            float gx = fminf(fmaxf(tx/239.0f*2.0f - 1.0f, -1.1f), 1.1f);
            float gy = fminf(fmaxf(ty/127.0f*2.0f - 1.0f, -1.1f), 1.1f);

            float ixf = (gx + 1.0f)*(FW*0.5f) - 0.5f;
            float iyf = (gy + 1.0f)*(FH*0.5f) - 0.5f;
            float x0f = floorf(ixf), y0f = floorf(iyf);
            float wx1 = ixf - x0f,  wy1 = iyf - y0f;
            float wx0 = 1.0f - wx1, wy0 = 1.0f - wy1;
            int x0 = (int)x0f, y0 = (int)y0f;
            int x1 = x0 + 1,   y1 = y0 + 1;
            bool vx0 = (x0 >= 0) & (x0 <= FW-1);
            bool vx1 = (x1 >= 0) & (x1 <= FW-1);
            bool vy0 = (y0 >= 0) & (y0 <= FH-1);
            bool vy1 = (y1 >= 0) & (y1 <= FH-1);
            float w00 = wx0*wy0*(float)(vx0 & vy0);
            float w10 = wx1*wy0*(float)(vx1 & vy0);
            float w01 = wx0*wy1*(float)(vx0 & vy1);
            float w11 = wx1*wy1*(float)(vx1 & vy1);
            int xc0 = min(max(x0,0),FW-1), xc1 = min(max(x1,0),FW-1);
            int yc0 = min(max(y0,0),FH-1), yc1 = min(max(y1,0),FH-1);
            int o00 = yc0*FW + xc0, o10 = yc0*FW + xc1;
            int o01 = yc1*FW + xc0, o11 = yc1*FW + xc1;

            const __half* base = fmH + ((size_t)(cam*B + b)) * HW * NCP;

            #define DO_TAP(Wt, Ot)                                            \
            {                                                                 \
                const uint4* tp = (const uint4*)(base + (size_t)(Ot) * NCP);  \
                uint4 A = tp[0], Bv = tp[1];                                  \
                uint wds[8] = {A.x, A.y, A.z, A.w, Bv.x, Bv.y, Bv.z, Bv.w};   \
                _Pragma("unroll")                                             \
                for (int q = 0; q < 8; ++q) {                                 \
                    __half2 h = *(const __half2*)&wds[q];                     \
                    float2 f = __half22float2(h);                             \
                    acc[2*q+0] = fmaf((Wt), f.x, acc[2*q+0]);                 \
                    acc[2*q+1] = fmaf((Wt), f.y, acc[2*q+1]);                 \
                }                                                             \
            }
            DO_TAP(w00, o00)
            DO_TAP(w10, o10)
            DO_TAP(w01, o01)
            DO_TAP(w11, o11)
            #undef DO_TAP
        }
    }

    const float invd = (float)(5.0 + 1e-6);
    #pragma unroll
    for (int c = 0; c < NC; ++c) {
        float v = acc[c] / invd;
        v = fminf(fmaxf(v, 0.0f), 1.0f);
        out[((size_t)(b*NC + c)) * NVOX + n] = v;
    }
}

// ---- fallback (round-1 kernel) if ws is too small for staging ----
__global__ __launch_bounds__(THREADS) void proj_fallback(
    const float* __restrict__ fm,
    const float* __restrict__ gc,
    const float* __restrict__ space_center,
    const float* __restrict__ space_size,
    const float* __restrict__ sub_size,
    const float* __restrict__ centers,
    const float* __restrict__ trans,
    const float* __restrict__ cam_R,
    const float* __restrict__ cam_T,
    const float* __restrict__ cam_f,
    const float* __restrict__ cam_c,
    float* __restrict__ out, int B)
{
    const int b = blockIdx.x / BLOCKS_PER_B;
    const int n = (blockIdx.x % BLOCKS_PER_B) * THREADS + threadIdx.x;

    float ctlf[3], fnf[3], sc[3], ssz[3];
    int   ctl[3], st[3], en[3];
    #pragma unroll
    for (int d = 0; d < 3; ++d) {
        ssz[d] = space_size[d];
        sc[d]  = space_center[d];
        float sub = sub_size[d];
        int fn = (int)(ssz[d] / sub * (CUBE - 1.0f)) + 1;
        fnf[d] = (float)fn;
        float scale = (fnf[d] - 1.0f) / ssz[d];
        float bias  = -sub / 2.0f / ssz[d] * (fnf[d] - 1.0f)
                      - scale * (sc[d] - ssz[d] / 2.0f);
        int c_tl = (int)rintf(gc[b*7 + d] * scale + bias);
        ctl[d]  = c_tl;
        ctlf[d] = (float)c_tl;
        int mask = 0;
        if (d < 2) {
            mask = (int)((1.0f - gc[b*7 + 5 + d]) / 2.0f * (CUBE - 1.0f));
            if (mask < 0) mask = 0;
        }
        st[d] = max(c_tl + mask, 0);
        int e = min(c_tl + CUBE - mask, fn);
        en[d] = max(e, st[d] + 1);
    }
    if (n < 3) {
        int d = n;
        float off = ctlf[d] / (fnf[d] - 1.0f) * ssz[d]
                    - ssz[d] / 2.0f + sub_size[d] / 2.0f;
        out[(size_t)B * NC * NVOX + b*3 + d] = off;
    }
    const int vi = n >> 12, vj = (n >> 6) & 63, vk = n & 63;
    const int fx = ctl[0] + vi, fy = ctl[1] + vj, fz = ctl[2] + vk;
    const bool valid = (fx >= st[0]) & (fx < en[0])
                     & (fy >= st[1]) & (fy < en[1])
                     & (fz >= st[2]) & (fz < en[2])
                     & (gc[b*7 + 3] >= 0.0f);
    float acc[NC];
    #pragma unroll
    for (int c = 0; c < NC; ++c) acc[c] = 0.0f;
    if (valid) {
        const float wxw = sc[0] - ssz[0]*0.5f + (float)fx / (fnf[0]-1.0f) * ssz[0];
        const float wyw = sc[1] - ssz[1]*0.5f + (float)fy / (fnf[1]-1.0f) * ssz[1];
        const float wzw = sc[2] - ssz[2]*0.5f + (float)fz / (fnf[2]-1.0f) * ssz[2];
        for (int cam = 0; cam < NCAM; ++cam) {
            const int bk = b*NCAM + cam;
            const float* R = cam_R + bk*9;
            const float* T = cam_T + bk*3;
            float r0 = wxw - T[0], r1 = wyw - T[1], r2 = wzw - T[2];
            float X0 = R[0]*r0 + R[1]*r1 + R[2]*r2;
            float X1 = R[3]*r0 + R[4]*r1 + R[5]*r2;
            float X2 = R[6]*r0 + R[7]*r1 + R[8]*r2;
            float px = cam_f[bk*2+0]*X0/X2 + cam_c[bk*2+0];
            float py = cam_f[bk*2+1]*X1/X2 + cam_c[bk*2+1];
            float maxwh = fmaxf(centers[bk*2+0]*2.0f, centers[bk*2+1]*2.0f);
            px = fminf(fmaxf(px, -1.0f), maxwh);
            py = fminf(fmaxf(py, -1.0f), maxwh);
            const float* tr = trans + bk*6;
            float tx = (tr[0]*px + tr[1]*py + tr[2]) * 0.25f;
            float ty = (tr[3]*px + tr[4]*py + tr[5]) * 0.25f;
            float gx = fminf(fmaxf(tx/239.0f*2.0f - 1.0f, -1.1f), 1.1f);
            float gy = fminf(fmaxf(ty/127.0f*2.0f - 1.0f, -1.1f), 1.1f);
            float ixf = (gx + 1.0f)*(FW*0.5f) - 0.5f;
            float iyf = (gy + 1.0f)*(FH*0.5f) - 0.5f;
            float x0f = floorf(ixf), y0f = floorf(iyf);
            float wx1 = ixf - x0f,  wy1 = iyf - y0f;
            float wx0 = 1.0f - wx1, wy0 = 1.0f - wy1;
            int x0 = (int)x0f, y0 = (int)y0f;
            int x1 = x0 + 1,   y1 = y0 + 1;
            bool vx0 = (x0 >= 0) & (x0 <= FW-1);
            bool vx1 = (x1 >= 0) & (x1 <= FW-1);
            bool vy0 = (y0 >= 0) & (y0 <= FH-1);
            bool vy1 = (y1 >= 0) & (y1 <= FH-1);
            float w00 = wx0*wy0*(float)(vx0 & vy0);
            float w10 = wx1*wy0*(float)(vx1 & vy0);
            float w01 = wx0*wy1*(float)(vx0 & vy1);
            float w11 = wx1*wy1*(float)(vx1 & vy1);
            int xc0 = min(max(x0,0),FW-1), xc1 = min(max(x1,0),FW-1);
            int yc0 = min(max(y0,0),FH-1), yc1 = min(max(y1,0),FH-1);
            int o00 = yc0*FW + xc0, o10 = yc0*FW + xc1;
            int o01 = yc1*FW + xc0, o11 = yc1*FW + xc1;
            const float* base = fm + ((size_t)(cam*B + b)) * NC * HW;
            #pragma unroll
            for (int c = 0; c < NC; ++c) {
                const float* p = base + c*HW;
                acc[c] += w00*p[o00] + w10*p[o10] + w01*p[o01] + w11*p[o11];
            }
        }
    }
    const float invd = (float)(5.0 + 1e-6);
    #pragma unroll
    for (int c = 0; c < NC; ++c) {
        float v = acc[c] / invd;
        v = fminf(fmaxf(v, 0.0f), 1.0f);
        out[((size_t)(b*NC + c)) * NVOX + n] = v;
    }
}

extern "C" void kernel_launch(void* const* d_in, const int* in_sizes, int n_in,
                              void* d_out, int out_size, void* d_ws, size_t ws_size,
                              hipStream_t stream) {
    const float* fm        = (const float*)d_in[0];
    const float* gc        = (const float*)d_in[1];
    const float* space_c   = (const float*)d_in[2];
    const float* space_s   = (const float*)d_in[3];
    const float* sub_s     = (const float*)d_in[4];
    const float* centers   = (const float*)d_in[6];
    const float* trans     = (const float*)d_in[7];
    const float* cam_R     = (const float*)d_in[8];
    const float* cam_T     = (const float*)d_in[9];
    const float* cam_f     = (const float*)d_in[10];
    const float* cam_c     = (const float*)d_in[11];
    float* out = (float*)d_out;
    const int B = in_sizes[1] / 7;

    const size_t need = (size_t)NCAM * B * HW * NCP * sizeof(__half);
    if (ws_size >= need) {
        __half* fmH = (__half*)d_ws;
        dim3 tg(HW / THREADS, NCAM * B);
        hipLaunchKernelGGL(transpose_fm, tg, dim3(THREADS), 0, stream, fm, fmH);
        dim3 grid(B * BLOCKS_PER_B), block(THREADS);
        hipLaunchKernelGGL(proj_main, grid, block, 0, stream,
                           fmH, gc, space_c, space_s, sub_s,
                           centers, trans, cam_R, cam_T, cam_f, cam_c, out, B);
    } else {
        dim3 grid(B * BLOCKS_PER_B), block(THREADS);
        hipLaunchKernelGGL(proj_fallback, grid, block, 0, stream,
                           fm, gc, space_c, space_s, sub_s,
                           centers, trans, cam_R, cam_T, cam_f, cam_c, out, B);
    }
}

// Round 4
// 43.799 us; speedup vs baseline: 3.3476x; 1.2536x over previous
//
#include <hip/hip_runtime.h>
#include <hip/hip_fp16.h>

#define NCAM 5
#define NC 15
#define NCP 16              // padded channels; fp16 -> 32 B per pixel
#define FH 128
#define FW 240
#define HW (FH*FW)
#define CUBE 64
#define NVOX (CUBE*CUBE*CUBE)
#define THREADS 256
#define BLOCKS_PER_B (NVOX/THREADS)   // 1024

// ---- pre-pass: [cam][b][c][h][w] f32 -> [cam][b][h][w][16] f16 (channel-last)
__global__ __launch_bounds__(THREADS) void transpose_fm(
    const float* __restrict__ fm, __half* __restrict__ fmH)
{
    const int p  = blockIdx.x * THREADS + threadIdx.x;  // pixel in (cam,b)
    const int cb = blockIdx.y;                          // cam*B + b
    const float* src = fm + (size_t)cb * NC * HW + p;
    __half v[NCP];
    #pragma unroll
    for (int c = 0; c < NC; ++c) v[c] = __float2half(src[(size_t)c * HW]);
    v[15] = __float2half(0.0f);
    uint4* dst = (uint4*)(fmH + ((size_t)cb * HW + p) * NCP);
    dst[0] = *(const uint4*)(v);
    dst[1] = *(const uint4*)(v + 8);
}

// fused f16->f32 multiply-add: acc += wt * half(lo/hi of wrd)
#define FMA_MIX2(lo, hi, wt, wrd)                                             \
    asm("v_fma_mix_f32 %0, %1, %2, %0 op_sel_hi:[0,1,0]"                      \
        : "+v"(lo) : "v"(wt), "v"(wrd));                                      \
    asm("v_fma_mix_f32 %0, %1, %2, %0 op_sel:[0,1,0] op_sel_hi:[0,1,0]"       \
        : "+v"(hi) : "v"(wt), "v"(wrd));

#define TAPFMA(wt, A, Bv)                                                     \
    FMA_MIX2(acc[0],  acc[1],  wt, A.x)                                       \
    FMA_MIX2(acc[2],  acc[3],  wt, A.y)                                       \
    FMA_MIX2(acc[4],  acc[5],  wt, A.z)                                       \
    FMA_MIX2(acc[6],  acc[7],  wt, A.w)                                       \
    FMA_MIX2(acc[8],  acc[9],  wt, Bv.x)                                      \
    FMA_MIX2(acc[10], acc[11], wt, Bv.y)                                      \
    FMA_MIX2(acc[12], acc[13], wt, Bv.z)                                      \
    FMA_MIX2(acc[14], acc[15], wt, Bv.w)

// ---- main kernel: one thread per (b, voxel), fp16 channel-last gathers
__global__ __launch_bounds__(THREADS) void proj_main(
    const __half* __restrict__ fmH,      // [NCAM][B][HW][16] f16
    const float* __restrict__ gc,        // [B][7]
    const float* __restrict__ space_center,
    const float* __restrict__ space_size,
    const float* __restrict__ sub_size,
    const float* __restrict__ centers,
    const float* __restrict__ trans,
    const float* __restrict__ cam_R,
    const float* __restrict__ cam_T,
    const float* __restrict__ cam_f,
    const float* __restrict__ cam_c,
    float* __restrict__ out, int B)
{
    const int b = blockIdx.x / BLOCKS_PER_B;
    const int n = (blockIdx.x % BLOCKS_PER_B) * THREADS + threadIdx.x;

    float ctlf[3], fnf[3], sc[3], ssz[3];
    int   ctl[3], st[3], en[3];
    #pragma unroll
    for (int d = 0; d < 3; ++d) {
        ssz[d] = space_size[d];
        sc[d]  = space_center[d];
        float sub = sub_size[d];
        int fn = (int)(ssz[d] / sub * (CUBE - 1.0f)) + 1;   // host-rare, keep exact div
        fnf[d] = (float)fn;
        float scale = (fnf[d] - 1.0f) / ssz[d];
        float bias  = -sub / 2.0f / ssz[d] * (fnf[d] - 1.0f)
                      - scale * (sc[d] - ssz[d] / 2.0f);
        int c_tl = (int)rintf(gc[b*7 + d] * scale + bias);
        ctl[d]  = c_tl;
        ctlf[d] = (float)c_tl;
        int mask = 0;
        if (d < 2) {
            mask = (int)((1.0f - gc[b*7 + 5 + d]) / 2.0f * (CUBE - 1.0f));
            if (mask < 0) mask = 0;
        }
        st[d] = max(c_tl + mask, 0);
        int e = min(c_tl + CUBE - mask, fn);
        en[d] = max(e, st[d] + 1);
    }

    if (n < 3) {
        int d = n;
        float off = ctlf[d] / (fnf[d] - 1.0f) * ssz[d]
                    - ssz[d] / 2.0f + sub_size[d] / 2.0f;
        out[(size_t)B * NC * NVOX + b*3 + d] = off;
    }

    const int vi = n >> 12, vj = (n >> 6) & 63, vk = n & 63;
    const int fx = ctl[0] + vi, fy = ctl[1] + vj, fz = ctl[2] + vk;
    const bool valid = (fx >= st[0]) & (fx < en[0])
                     & (fy >= st[1]) & (fy < en[1])
                     & (fz >= st[2]) & (fz < en[2])
                     & (gc[b*7 + 3] >= 0.0f);

    float acc[NCP];
    #pragma unroll
    for (int c = 0; c < NCP; ++c) acc[c] = 0.0f;

    if (valid) {
        const float wxw = sc[0] - ssz[0]*0.5f + (float)fx / (fnf[0]-1.0f) * ssz[0];
        const float wyw = sc[1] - ssz[1]*0.5f + (float)fy / (fnf[1]-1.0f) * ssz[1];
        const float wzw = sc[2] - ssz[2]*0.5f + (float)fz / (fnf[2]-1.0f) * ssz[2];
        const float GXS = 2.0f / 239.0f;   // replaces /239*2
        const float GYS = 2.0f / 127.0f;   // replaces /127*2

        for (int cam = 0; cam < NCAM; ++cam) {
            const int bk = b*NCAM + cam;
            const float* R = cam_R + bk*9;
            const float* T = cam_T + bk*3;
            float r0 = wxw - T[0], r1 = wyw - T[1], r2 = wzw - T[2];
            float X0 = R[0]*r0 + R[1]*r1 + R[2]*r2;
            float X1 = R[3]*r0 + R[4]*r1 + R[5]*r2;
            float X2 = R[6]*r0 + R[7]*r1 + R[8]*r2;
            float rz = __builtin_amdgcn_rcpf(X2);            // ~1ulp, replaces IEEE div
            float px = (cam_f[bk*2+0]*X0)*rz + cam_c[bk*2+0];
            float py = (cam_f[bk*2+1]*X1)*rz + cam_c[bk*2+1];
            float maxwh = fmaxf(centers[bk*2+0]*2.0f, centers[bk*2+1]*2.0f);
            px = fminf(fmaxf(px, -1.0f), maxwh);
            py = fminf(fmaxf(py, -1.0f), maxwh);
            const float* tr = trans + bk*6;
            float tx = (tr[0]*px + tr[1]*py + tr[2]) * 0.25f;   // HM_W/IMG_W (exact)
            float ty = (tr[3]*px + tr[4]*py + tr[5]) * 0.25f;   // HM_H/IMG_H (exact)
            float gx = fminf(fmaxf(tx*GXS - 1.0f, -1.1f), 1.1f);
            float gy = fminf(fmaxf(ty*GYS - 1.0f, -1.1f), 1.1f);

            float ixf = (gx + 1.0f)*(FW*0.5f) - 0.5f;
            float iyf = (gy + 1.0f)*(FH*0.5f) - 0.5f;
            float x0f = floorf(ixf), y0f = floorf(iyf);
            float wx1 = ixf - x0f,  wy1 = iyf - y0f;
            float wx0 = 1.0f - wx1, wy0 = 1.0f - wy1;
            int x0 = (int)x0f, y0 = (int)y0f;
            int x1 = x0 + 1,   y1 = y0 + 1;
            bool vx0 = (x0 >= 0) & (x0 <= FW-1);
            bool vx1 = (x1 >= 0) & (x1 <= FW-1);
            bool vy0 = (y0 >= 0) & (y0 <= FH-1);
            bool vy1 = (y1 >= 0) & (y1 <= FH-1);
            float w00 = wx0*wy0*(float)(vx0 & vy0);
            float w10 = wx1*wy0*(float)(vx1 & vy0);
            float w01 = wx0*wy1*(float)(vx0 & vy1);
            float w11 = wx1*wy1*(float)(vx1 & vy1);
            int xc0 = min(max(x0,0),FW-1), xc1 = min(max(x1,0),FW-1);
            int yc0 = min(max(y0,0),FH-1), yc1 = min(max(y1,0),FH-1);
            int o00 = yc0*FW + xc0, o10 = yc0*FW + xc1;
            int o01 = yc1*FW + xc0, o11 = yc1*FW + xc1;

            const __half* base = fmH + ((size_t)(cam*B + b)) * HW * NCP;
            const uint4* p00 = (const uint4*)(base + (size_t)o00 * NCP);
            const uint4* p10 = (const uint4*)(base + (size_t)o10 * NCP);
            const uint4* p01 = (const uint4*)(base + (size_t)o01 * NCP);
            const uint4* p11 = (const uint4*)(base + (size_t)o11 * NCP);
            // cluster the 8 loads so they overlap
            uint4 a0 = p00[0], b0 = p00[1];
            uint4 a1 = p10[0], b1 = p10[1];
            uint4 a2 = p01[0], b2 = p01[1];
            uint4 a3 = p11[0], b3 = p11[1];

            TAPFMA(w00, a0, b0)
            TAPFMA(w10, a1, b1)
            TAPFMA(w01, a2, b2)
            TAPFMA(w11, a3, b3)
        }
    }

    const float RINV = 0.19999996000000800f;  // 1/(5+1e-6), replaces 15 IEEE divs
    #pragma unroll
    for (int c = 0; c < NC; ++c) {
        float v = acc[c] * RINV;
        v = fminf(fmaxf(v, 0.0f), 1.0f);
        out[((size_t)(b*NC + c)) * NVOX + n] = v;
    }
}

// ---- fallback (round-1 kernel) if ws is too small for staging ----
__global__ __launch_bounds__(THREADS) void proj_fallback(
    const float* __restrict__ fm,
    const float* __restrict__ gc,
    const float* __restrict__ space_center,
    const float* __restrict__ space_size,
    const float* __restrict__ sub_size,
    const float* __restrict__ centers,
    const float* __restrict__ trans,
    const float* __restrict__ cam_R,
    const float* __restrict__ cam_T,
    const float* __restrict__ cam_f,
    const float* __restrict__ cam_c,
    float* __restrict__ out, int B)
{
    const int b = blockIdx.x / BLOCKS_PER_B;
    const int n = (blockIdx.x % BLOCKS_PER_B) * THREADS + threadIdx.x;
    float ctlf[3], fnf[3], sc[3], ssz[3];
    int   ctl[3], st[3], en[3];
    #pragma unroll
    for (int d = 0; d < 3; ++d) {
        ssz[d] = space_size[d];
        sc[d]  = space_center[d];
        float sub = sub_size[d];
        int fn = (int)(ssz[d] / sub * (CUBE - 1.0f)) + 1;
        fnf[d] = (float)fn;
        float scale = (fnf[d] - 1.0f) / ssz[d];
        float bias  = -sub / 2.0f / ssz[d] * (fnf[d] - 1.0f)
                      - scale * (sc[d] - ssz[d] / 2.0f);
        int c_tl = (int)rintf(gc[b*7 + d] * scale + bias);
        ctl[d]  = c_tl;
        ctlf[d] = (float)c_tl;
        int mask = 0;
        if (d < 2) {
            mask = (int)((1.0f - gc[b*7 + 5 + d]) / 2.0f * (CUBE - 1.0f));
            if (mask < 0) mask = 0;
        }
        st[d] = max(c_tl + mask, 0);
        int e = min(c_tl + CUBE - mask, fn);
        en[d] = max(e, st[d] + 1);
    }
    if (n < 3) {
        int d = n;
        float off = ctlf[d] / (fnf[d] - 1.0f) * ssz[d]
                    - ssz[d] / 2.0f + sub_size[d] / 2.0f;
        out[(size_t)B * NC * NVOX + b*3 + d] = off;
    }
    const int vi = n >> 12, vj = (n >> 6) & 63, vk = n & 63;
    const int fx = ctl[0] + vi, fy = ctl[1] + vj, fz = ctl[2] + vk;
    const bool valid = (fx >= st[0]) & (fx < en[0])
                     & (fy >= st[1]) & (fy < en[1])
                     & (fz >= st[2]) & (fz < en[2])
                     & (gc[b*7 + 3] >= 0.0f);
    float acc[NC];
    #pragma unroll
    for (int c = 0; c < NC; ++c) acc[c] = 0.0f;
    if (valid) {
        const float wxw = sc[0] - ssz[0]*0.5f + (float)fx / (fnf[0]-1.0f) * ssz[0];
        const float wyw = sc[1] - ssz[1]*0.5f + (float)fy / (fnf[1]-1.0f) * ssz[1];
        const float wzw = sc[2] - ssz[2]*0.5f + (float)fz / (fnf[2]-1.0f) * ssz[2];
        for (int cam = 0; cam < NCAM; ++cam) {
            const int bk = b*NCAM + cam;
            const float* R = cam_R + bk*9;
            const float* T = cam_T + bk*3;
            float r0 = wxw - T[0], r1 = wyw - T[1], r2 = wzw - T[2];
            float X0 = R[0]*r0 + R[1]*r1 + R[2]*r2;
            float X1 = R[3]*r0 + R[4]*r1 + R[5]*r2;
            float X2 = R[6]*r0 + R[7]*r1 + R[8]*r2;
            float px = cam_f[bk*2+0]*X0/X2 + cam_c[bk*2+0];
            float py = cam_f[bk*2+1]*X1/X2 + cam_c[bk*2+1];
            float maxwh = fmaxf(centers[bk*2+0]*2.0f, centers[bk*2+1]*2.0f);
            px = fminf(fmaxf(px, -1.0f), maxwh);
            py = fminf(fmaxf(py, -1.0f), maxwh);
            const float* tr = trans + bk*6;
            float tx = (tr[0]*px + tr[1]*py + tr[2]) * 0.25f;
            float ty = (tr[3]*px + tr[4]*py + tr[5]) * 0.25f;
            float gx = fminf(fmaxf(tx/239.0f*2.0f - 1.0f, -1.1f), 1.1f);
            float gy = fminf(fmaxf(ty/127.0f*2.0f - 1.0f, -1.1f), 1.1f);
            float ixf = (gx + 1.0f)*(FW*0.5f) - 0.5f;
            float iyf = (gy + 1.0f)*(FH*0.5f) - 0.5f;
            float x0f = floorf(ixf), y0f = floorf(iyf);
            float wx1 = ixf - x0f,  wy1 = iyf - y0f;
            float wx0 = 1.0f - wx1, wy0 = 1.0f - wy1;
            int x0 = (int)x0f, y0 = (int)y0f;
            int x1 = x0 + 1,   y1 = y0 + 1;
            bool vx0 = (x0 >= 0) & (x0 <= FW-1);
            bool vx1 = (x1 >= 0) & (x1 <= FW-1);
            bool vy0 = (y0 >= 0) & (y0 <= FH-1);
            bool vy1 = (y1 >= 0) & (y1 <= FH-1);
            float w00 = wx0*wy0*(float)(vx0 & vy0);
            float w10 = wx1*wy0*(float)(vx1 & vy0);
            float w01 = wx0*wy1*(float)(vx0 & vy1);
            float w11 = wx1*wy1*(float)(vx1 & vy1);
            int xc0 = min(max(x0,0),FW-1), xc1 = min(max(x1,0),FW-1);
            int yc0 = min(max(y0,0),FH-1), yc1 = min(max(y1,0),FH-1);
            int o00 = yc0*FW + xc0, o10 = yc0*FW + xc1;
            int o01 = yc1*FW + xc0, o11 = yc1*FW + xc1;
            const float* base = fm + ((size_t)(cam*B + b)) * NC * HW;
            #pragma unroll
            for (int c = 0; c < NC; ++c) {
                const float* p = base + c*HW;
                acc[c] += w00*p[o00] + w10*p[o10] + w01*p[o01] + w11*p[o11];
            }
        }
    }
    const float invd = (float)(5.0 + 1e-6);
    #pragma unroll
    for (int c = 0; c < NC; ++c) {
        float v = acc[c] / invd;
        v = fminf(fmaxf(v, 0.0f), 1.0f);
        out[((size_t)(b*NC + c)) * NVOX + n] = v;
    }
}

extern "C" void kernel_launch(void* const* d_in, const int* in_sizes, int n_in,
                              void* d_out, int out_size, void* d_ws, size_t ws_size,
                              hipStream_t stream) {
    const float* fm        = (const float*)d_in[0];
    const float* gc        = (const float*)d_in[1];
    const float* space_c   = (const float*)d_in[2];
    const float* space_s   = (const float*)d_in[3];
    const float* sub_s     = (const float*)d_in[4];
    const float* centers   = (const float*)d_in[6];
    const float* trans     = (const float*)d_in[7];
    const float* cam_R     = (const float*)d_in[8];
    const float* cam_T     = (const float*)d_in[9];
    const float* cam_f     = (const float*)d_in[10];
    const float* cam_c     = (const float*)d_in[11];
    float* out = (float*)d_out;
    const int B = in_sizes[1] / 7;

    const size_t need = (size_t)NCAM * B * HW * NCP * sizeof(__half);
    if (ws_size >= need) {
        __half* fmH = (__half*)d_ws;
        dim3 tg(HW / THREADS, NCAM * B);
        hipLaunchKernelGGL(transpose_fm, tg, dim3(THREADS), 0, stream, fm, fmH);
        dim3 grid(B * BLOCKS_PER_B), block(THREADS);
        hipLaunchKernelGGL(proj_main, grid, block, 0, stream,
                           fmH, gc, space_c, space_s, sub_s,
                           centers, trans, cam_R, cam_T, cam_f, cam_c, out, B);
    } else {
        dim3 grid(B * BLOCKS_PER_B), block(THREADS);
        hipLaunchKernelGGL(proj_fallback, grid, block, 0, stream,
                           fm, gc, space_c, space_s, sub_s,
                           centers, trans, cam_R, cam_T, cam_f, cam_c, out, B);
    }
}